// Round 14
// baseline (111.821 us; speedup 1.0000x reference)
//
#include <hip/hip_runtime.h>
#include <hip/hip_bf16.h>

// ddstgcn via conv/diffusion commutation:
//   y = proj0(x) + bias + sum_s A_s @ ( p1_s(x) + A_s @ p2_s(x) )
// K0 xpose  : x -> xq bf16; +512 warm blocks streaming A0,A1 into L3 (16-deep MLP)
// K1 proj_x : 7 projections MFMA -> P1, P2, proj0 (bf16); +256 warm blocks for A2
// K2 gemm_t : T := P1 + A_s @ P2 (in-place over P1)  [A L3-warm]
// K3 gemm_yp: Ypart[z] = A_s @ T_s (bf16)
// K4 reduce : y = bias + proj0 + sum_s Ypart[s]

typedef unsigned short u16;
typedef u16 u16x4 __attribute__((ext_vector_type(4)));
typedef u16 u16x8 __attribute__((ext_vector_type(8)));
typedef __bf16 bf16x8 __attribute__((ext_vector_type(8)));
typedef float f32x4 __attribute__((ext_vector_type(4)));

#define GLD_LDS16(g, l)  __builtin_amdgcn_global_load_lds( \
    (const __attribute__((address_space(1))) void*)(g),    \
    (__attribute__((address_space(3))) void*)(l), 16, 0, 0)

__device__ __forceinline__ u16 f2bf(float f) {
    unsigned int u = __float_as_uint(f);
    u += 0x7fffu + ((u >> 16) & 1u);   // RNE
    return (u16)(u >> 16);
}
__device__ __forceinline__ float bf2f(u16 h) {
    return __uint_as_float(((unsigned int)h) << 16);
}

// warm 131072 B into cache: 2 batches x 16 statically-named float4 loads per
// thread (16 outstanding -> 16KB/wave in flight), sink via asm (rule #17).
__device__ __forceinline__ void warm_range(const float4* __restrict__ p, int t) {
    #pragma unroll
    for (int bat = 0; bat < 2; ++bat) {
        float4 v[16];
        #pragma unroll
        for (int j = 0; j < 16; ++j)
            v[j] = p[bat * 4096 + j * 256 + t];
        #pragma unroll
        for (int j = 0; j < 16; ++j)
            asm volatile("" :: "v"(v[j].x), "v"(v[j].y), "v"(v[j].z), "v"(v[j].w));
    }
}

// ---------------- K0: x[b,c,v,l] f32 -> xq[b][l][v][48] bf16 (+A0/A1 warm) ----------------
__global__ __launch_bounds__(256) void xpose(const float* __restrict__ x,
                                             const float* __restrict__ A0,
                                             const float* __restrict__ A1,
                                             u16* __restrict__ xq)
{
    if (blockIdx.z != 0) {                 // 512 warm blocks: 256 for A0, 256 for A1
        int pb = (blockIdx.z - 1) * 256 + blockIdx.x + 8 * blockIdx.y;  // 0..511
        const float* src = (pb < 256) ? A0 : A1;
        warm_range((const float4*)src + (size_t)(pb & 255) * 8192, threadIdx.x);
        return;
    }
    const int t = threadIdx.x, vloc = t & 63, cg = t >> 6;
    const int v = blockIdx.x * 64 + vloc, b = blockIdx.y;

    u16 vals[12][12];
    #pragma unroll
    for (int ci = 0; ci < 12; ++ci) {
        int c = cg * 12 + ci;
        if (c < 40) {
            const float* xp = x + ((size_t)(b * 40 + c) * 512 + v) * 12;
            float4 f0 = *(const float4*)xp;
            float4 f1 = *(const float4*)(xp + 4);
            float4 f2 = *(const float4*)(xp + 8);
            vals[0][ci] = f2bf(f0.x);  vals[1][ci] = f2bf(f0.y);
            vals[2][ci] = f2bf(f0.z);  vals[3][ci] = f2bf(f0.w);
            vals[4][ci] = f2bf(f1.x);  vals[5][ci] = f2bf(f1.y);
            vals[6][ci] = f2bf(f1.z);  vals[7][ci] = f2bf(f1.w);
            vals[8][ci] = f2bf(f2.x);  vals[9][ci] = f2bf(f2.y);
            vals[10][ci] = f2bf(f2.z); vals[11][ci] = f2bf(f2.w);
        } else {
            #pragma unroll
            for (int l = 0; l < 12; ++l) vals[l][ci] = 0;
        }
    }
    #pragma unroll
    for (int l = 0; l < 12; ++l) {
        u16* dst = xq + ((size_t)(b * 12 + l) * 512 + v) * 48 + cg * 12;
        u16x4 a = { vals[l][0], vals[l][1], vals[l][2], vals[l][3] };
        u16x4 c4 = { vals[l][4], vals[l][5], vals[l][6], vals[l][7] };
        u16x4 d = { vals[l][8], vals[l][9], vals[l][10], vals[l][11] };
        *(u16x4*)(dst) = a;
        *(u16x4*)(dst + 4) = c4;
        *(u16x4*)(dst + 8) = d;
    }
}

// ---------------- K1: fused 7-way projection of x (+A2 warm) ----------------
__global__ __launch_bounds__(256) void proj_x(
    const u16* __restrict__ xq, const float* __restrict__ W,
    const float* __restrict__ A2,
    u16* __restrict__ P1, u16* __restrict__ P2, u16* __restrict__ proj0)
{
    __shared__ u16 sA[144 * 104];
    __shared__ u16 sB[2][2 * 64 * 48];

    if (blockIdx.z == 1) {                 // 256 warm blocks for A2 (33.5 MB)
        int pb = blockIdx.x + 8 * blockIdx.y;
        warm_range((const float4*)A2 + (size_t)pb * 8192, threadIdx.x);
        return;
    }

    const int t = threadIdx.x, lane = t & 63, wid = t >> 6;
    const int b = blockIdx.y, v0 = blockIdx.x * 64;

    for (int id = t; id < 144 * 5; id += 256) {
        int m = id / 5, c0 = (id % 5) * 8;
        u16x8 e = {}, o8 = {};
        if (m < 140) {
            int o = m % 20, sg = m / 20;
            const float* wp = W + o * 560 + sg * 80 + c0 * 2;
            float4 a = *(const float4*)wp;
            float4 bb = *(const float4*)(wp + 4);
            float4 c = *(const float4*)(wp + 8);
            float4 d = *(const float4*)(wp + 12);
            e[0] = f2bf(a.x);  o8[0] = f2bf(a.y);  e[1] = f2bf(a.z);  o8[1] = f2bf(a.w);
            e[2] = f2bf(bb.x); o8[2] = f2bf(bb.y); e[3] = f2bf(bb.z); o8[3] = f2bf(bb.w);
            e[4] = f2bf(c.x);  o8[4] = f2bf(c.y);  e[5] = f2bf(c.z);  o8[5] = f2bf(c.w);
            e[6] = f2bf(d.x);  o8[6] = f2bf(d.y);  e[7] = f2bf(d.z);  o8[7] = f2bf(d.w);
        }
        *(u16x8*)(&sA[m * 104 + c0]) = e;
        *(u16x8*)(&sA[m * 104 + 40 + c0]) = o8;
    }
    for (int id = t; id < 144 * 3; id += 256) {
        int m = id / 3, k0 = 80 + (id % 3) * 8;
        u16x8 z = {};
        *(u16x8*)(&sA[m * 104 + k0]) = z;
    }

    auto stage = [&](int l, int buf) {
        u16* dst = &sB[buf][0];
        #pragma unroll
        for (int i = 0; i < 3; ++i) {
            int op = wid * 3 + i;
            int tap = op / 6, rem = op % 6;
            const u16* src = xq + ((size_t)(b * 12 + l + 2 * tap) * 512 + v0) * 48
                             + rem * 512 + lane * 8;
            GLD_LDS16(src, dst + tap * 3072 + rem * 512);
        }
    };

    stage(0, 0);
    __syncthreads();

    const int lr = lane & 15, q = lane >> 4;
    bf16x8 af[9][3];
    #pragma unroll
    for (int mf = 0; mf < 9; ++mf)
        #pragma unroll
        for (int s = 0; s < 3; ++s)
            af[mf][s] = *(const bf16x8*)(&sA[(mf * 16 + lr) * 104 + s * 32 + q * 8]);

    const int voff = (wid * 16 + lr) * 48;
    int boff[3];
    #pragma unroll
    for (int s = 0; s < 3; ++s) {
        int k = s * 32 + q * 8;
        int tap, c;
        if (k < 40)      { tap = 0; c = k; }
        else if (k < 80) { tap = 1; c = k - 40; }
        else             { tap = 1; c = 40; }
        boff[s] = tap * 3072 + voff + c;
    }

    const int v = v0 + wid * 16 + lr;
    for (int l = 0; l < 10; ++l) {
        const int cur = l & 1;
        if (l < 9) stage(l + 1, cur ^ 1);

        const u16* bb = &sB[cur][0];
        bf16x8 xf[3];
        #pragma unroll
        for (int s = 0; s < 3; ++s) xf[s] = *(const bf16x8*)(bb + boff[s]);

        f32x4 acc[9] = {};
        #pragma unroll
        for (int s = 0; s < 3; ++s)
            #pragma unroll
            for (int mf = 0; mf < 9; ++mf)
                acc[mf] = __builtin_amdgcn_mfma_f32_16x16x32_bf16(
                    af[mf][s], xf[s], acc[mf], 0, 0, 0);

        #pragma unroll
        for (int mf = 0; mf < 9; ++mf)
            #pragma unroll
            for (int i = 0; i < 4; ++i) {
                int m = mf * 16 + q * 4 + i;
                if (m < 140) {
                    int o = m % 20, sg = m / 20;
                    float val = acc[mf][i];
                    if (sg == 0) {
                        proj0[((size_t)(b * 20 + o) * 10 + l) * 512 + v] = f2bf(val);
                    } else {
                        int s2 = (sg - 1) >> 1;
                        u16* dst = ((sg - 1) & 1) ? P2 : P1;
                        dst[((size_t)(s2 * 32 + b) * 200 + o * 10 + l) * 512 + v] = f2bf(val);
                    }
                }
            }
        __syncthreads();
    }
}

// ---------------- shared GEMM body: 2-phase DMA double-buffer (R9, proven) ----------------
// tile 128v x 112col, BK=32, 16 K-steps, 4 waves (wave = 32v x 112col).
// LDS-transpose epilogue: EPI=0 adds P1 (in-place RMW); EPI=1 plain store.
template <int EPI>
__device__ __forceinline__ void gemm_body(
    const float* __restrict__ A0, const float* __restrict__ A1, const float* __restrict__ A2,
    const u16* __restrict__ Xsrc, u16* __restrict__ Odst)
{
    __shared__ float sAf[2][128 * 32];   // A f32, rows of 128B, chunk-XOR swizzled (32KB)
    __shared__ u16   sXs[2][112 * 32];   // X bf16, rows of 64B, linear (14KB)

    // XCD swizzle: 768 blocks -> XCD gets 96 consecutive eids = 12 whole z's
    const int bid = blockIdx.x;
    const int eid = (bid & 7) * 96 + (bid >> 3);
    const int z = eid >> 3, rem = eid & 7;
    const int vblk = (rem >> 1) * 128;
    const int colbase = (rem & 1) * 112;
    const int s = z >> 5, b = z & 31;

    const float* Af = (s == 0 ? A0 : (s == 1 ? A1 : A2)) + (size_t)b * 512 * 512;
    const u16* Xb = Xsrc + (size_t)z * 200 * 512;

    const int t = threadIdx.x;
    const int lane = t & 63, wid = t >> 6;
    const int lr = lane & 15, q = lane >> 4;
    const int kc0 = q * 2;                     // A chunk pair base (16B chunks)

    auto stage = [&](int kt, int buf) {
        const int w0 = kt * 32;
        float* ab = &sAf[buf][0];
        u16*   xb = &sXs[buf][0];
        #pragma unroll
        for (int i = 0; i < 4; ++i) {
            int op  = wid * 4 + i;
            int row = op * 8 + (lane >> 3);
            int pc  = lane & 7;
            const float* src = Af + (size_t)(vblk + row) * 512 + w0 + ((pc ^ (row & 7)) << 2);
            GLD_LDS16(src, ab + op * 256);
        }
        #pragma unroll
        for (int i = 0; i < 2; ++i) {
            int op = wid + i * 4;
            if (op < 7) {
                int row = op * 16 + (lane >> 2);
                int ch  = lane & 3;
                const u16* src = Xb + (size_t)(colbase + row) * 512 + w0 + ch * 8;
                GLD_LDS16(src, xb + op * 512);
            }
        }
    };

    f32x4 acc[7][2] = {};

    stage(0, 0);
    __syncthreads();

    for (int kt = 0; kt < 16; ++kt) {
        const int cur = kt & 1;
        if (kt < 15) stage(kt + 1, cur ^ 1);

        bf16x8 af[2];
        #pragma unroll
        for (int mf = 0; mf < 2; ++mf) {
            int r = wid * 32 + mf * 16 + lr;
            const float* rb = &sAf[cur][r * 32];
            f32x4 a0 = *(const f32x4*)(rb + ((kc0 ^ (r & 7)) << 2));
            f32x4 a1 = *(const f32x4*)(rb + (((kc0 + 1) ^ (r & 7)) << 2));
            union { u16x8 u; bf16x8 bv; } cv;
            cv.u = (u16x8){ f2bf(a0[0]), f2bf(a0[1]), f2bf(a0[2]), f2bf(a0[3]),
                            f2bf(a1[0]), f2bf(a1[1]), f2bf(a1[2]), f2bf(a1[3]) };
            af[mf] = cv.bv;
        }
        #pragma unroll
        for (int cf = 0; cf < 7; ++cf) {
            bf16x8 xf = *(const bf16x8*)(&sXs[cur][(cf * 16 + lr) * 32 + q * 8]);
            #pragma unroll
            for (int mf = 0; mf < 2; ++mf)
                acc[cf][mf] = __builtin_amdgcn_mfma_f32_16x16x32_bf16(
                    xf, af[mf], acc[cf][mf], 0, 0, 0);
        }
        __syncthreads();
    }

    // LDS-transpose epilogue: acc -> eb[col][v] (stride 140, bank-clean),
    // then coalesced u16x8 stores (EPI=0: += P1 in-place; EPI=1: plain).
    u16* eb = (u16*)&sAf[0][0];              // 112*140*2 = 31360 B <= 32 KB region
    #pragma unroll
    for (int cf = 0; cf < 7; ++cf)
        #pragma unroll
        for (int mf = 0; mf < 2; ++mf)
            #pragma unroll
            for (int i = 0; i < 4; ++i) {
                int col = cf * 16 + q * 4 + i;            // 0..111
                int vl  = wid * 32 + mf * 16 + lr;        // 0..127
                eb[col * 140 + vl] = f2bf(acc[cf][mf][i]);
            }
    __syncthreads();
    u16* Oz = Odst + (size_t)z * 200 * 512;
    for (int id = t; id < 112 * 16; id += 256) {
        int col = id >> 4, ch = id & 15;
        int rg = colbase + col;
        if (rg < 200) {
            u16x8 tv = *(const u16x8*)(&eb[col * 140 + ch * 8]);
            size_t gidx = (size_t)rg * 512 + vblk + ch * 8;
            if (EPI == 0) {
                u16x8 pv = *(const u16x8*)(Oz + gidx);
                u16x8 out;
                #pragma unroll
                for (int j = 0; j < 8; ++j) out[j] = f2bf(bf2f(tv[j]) + bf2f(pv[j]));
                *(u16x8*)(Oz + gidx) = out;
            } else {
                *(u16x8*)(Oz + gidx) = tv;
            }
        }
    }
}

__global__ __launch_bounds__(256) void gemm_t(
    const float* __restrict__ A0, const float* __restrict__ A1, const float* __restrict__ A2,
    const u16* __restrict__ P2, u16* __restrict__ T)
{
    gemm_body<0>(A0, A1, A2, P2, T);
}

__global__ __launch_bounds__(256) void gemm_yp(
    const float* __restrict__ A0, const float* __restrict__ A1, const float* __restrict__ A2,
    const u16* __restrict__ T, u16* __restrict__ Ypart)
{
    gemm_body<1>(A0, A1, A2, T, Ypart);
}

// ---------------- K4: y = bias + proj0 + sum_s Ypart[s] ----------------
__global__ __launch_bounds__(256) void reduce_y(
    const u16* __restrict__ Ypart, const u16* __restrict__ proj0,
    const float* __restrict__ bias, float* __restrict__ y)
{
    int i = blockIdx.x * 256 + threadIdx.x;   // over 32*20*512
    if (i >= 32 * 20 * 512) return;
    int v = i & 511;
    int r = i >> 9;                           // b*20 + o
    int o = r % 20, b = r / 20;
    float bb = bias[o];
    float* yp = y + ((size_t)r * 512 + v) * 10;
    #pragma unroll
    for (int l = 0; l < 10; ++l) {
        float sum = bb + bf2f(proj0[((size_t)r * 10 + l) * 512 + v]);
        #pragma unroll
        for (int s = 0; s < 3; ++s)
            sum += bf2f(Ypart[((size_t)(s * 32 + b) * 200 + o * 10 + l) * 512 + v]);
        yp[l] = sum;
    }
}

extern "C" void kernel_launch(void* const* d_in, const int* in_sizes, int n_in,
                              void* d_out, int out_size, void* d_ws, size_t ws_size,
                              hipStream_t stream) {
    const float* x    = (const float*)d_in[0];
    const float* A0   = (const float*)d_in[1];
    const float* A1   = (const float*)d_in[2];
    const float* A2   = (const float*)d_in[3];
    const float* W    = (const float*)d_in[4];
    const float* bias = (const float*)d_in[5];
    float* y = (float*)d_out;

    // ws (all bf16): P1/T 19.66MB | P2 19.66MB | proj0 6.55MB | Ypart 19.66MB
    // xq (18.87MB) aliases Ypart (dead before gemm_yp). Total 65.5MB.
    const size_t PSZ = (size_t)96 * 200 * 512;
    u16* P1 = (u16*)d_ws;
    u16* P2 = P1 + PSZ;
    u16* proj0 = P2 + PSZ;
    u16* Ypart = proj0 + (size_t)32 * 20 * 10 * 512;
    u16* xq = Ypart;                          // alias

    xpose<<<dim3(8, 32, 3), 256, 0, stream>>>(x, A0, A1, xq);
    proj_x<<<dim3(8, 32, 2), 256, 0, stream>>>(xq, W, A2, P1, P2, proj0);
    gemm_t<<<dim3(768), 256, 0, stream>>>(A0, A1, A2, P2, P1);       // T := P1 + A@P2
    gemm_yp<<<dim3(768), 256, 0, stream>>>(A0, A1, A2, P1, Ypart);   // Ypart = A@T
    reduce_y<<<dim3(1280), 256, 0, stream>>>(Ypart, proj0, bias, y);
}

// Round 15
// 100.371 us; speedup vs baseline: 1.1141x; 1.1141x over previous
//
#include <hip/hip_runtime.h>
#include <hip/hip_bf16.h>

// ddstgcn via conv/diffusion commutation:
//   y = proj0(x) + bias + sum_s A_s @ ( p1_s(x) + A_s @ p2_s(x) )
// K0 xpose  : x[b,c,v,l] f32 -> xq[b][l][v][48] bf16
// K1 proj_x : 7 projections as MFMA GEMM -> P1, P2, proj0 (all bf16, coalesced)
// K2 gemm_t : T := P1 + A_s @ P2 (in-place over P1)
// K3 gemm_yp: Ypart[z] = A_s @ T_s (bf16)
// K4 reduce : y = bias + proj0 + sum_s Ypart[s]
//
// Round-14: staged-bytes model (283 MB staged @5.4 TB/s explained gemm_t's 52us).
// Col-split removed: tile 128v x 224col -> A staged ONCE (100 MB, was 200),
// X x4 (77 MB) = 177 MB staged. Grid 384, LDS 60KB, 2 blocks/CU, all resident.

typedef unsigned short u16;
typedef u16 u16x4 __attribute__((ext_vector_type(4)));
typedef u16 u16x8 __attribute__((ext_vector_type(8)));
typedef __bf16 bf16x8 __attribute__((ext_vector_type(8)));
typedef float f32x4 __attribute__((ext_vector_type(4)));

#define GLD_LDS16(g, l)  __builtin_amdgcn_global_load_lds( \
    (const __attribute__((address_space(1))) void*)(g),    \
    (__attribute__((address_space(3))) void*)(l), 16, 0, 0)

__device__ __forceinline__ u16 f2bf(float f) {
    unsigned int u = __float_as_uint(f);
    u += 0x7fffu + ((u >> 16) & 1u);   // RNE
    return (u16)(u >> 16);
}
__device__ __forceinline__ float bf2f(u16 h) {
    return __uint_as_float(((unsigned int)h) << 16);
}

// ---------------- K0: x[b,c,v,l] f32 -> xq[b][l][v][48] bf16 ----------------
__global__ __launch_bounds__(256) void xpose(const float* __restrict__ x,
                                             u16* __restrict__ xq)
{
    const int t = threadIdx.x, vloc = t & 63, cg = t >> 6;
    const int v = blockIdx.x * 64 + vloc, b = blockIdx.y;

    u16 vals[12][12];
    #pragma unroll
    for (int ci = 0; ci < 12; ++ci) {
        int c = cg * 12 + ci;
        if (c < 40) {
            const float* xp = x + ((size_t)(b * 40 + c) * 512 + v) * 12;
            float4 f0 = *(const float4*)xp;
            float4 f1 = *(const float4*)(xp + 4);
            float4 f2 = *(const float4*)(xp + 8);
            vals[0][ci] = f2bf(f0.x);  vals[1][ci] = f2bf(f0.y);
            vals[2][ci] = f2bf(f0.z);  vals[3][ci] = f2bf(f0.w);
            vals[4][ci] = f2bf(f1.x);  vals[5][ci] = f2bf(f1.y);
            vals[6][ci] = f2bf(f1.z);  vals[7][ci] = f2bf(f1.w);
            vals[8][ci] = f2bf(f2.x);  vals[9][ci] = f2bf(f2.y);
            vals[10][ci] = f2bf(f2.z); vals[11][ci] = f2bf(f2.w);
        } else {
            #pragma unroll
            for (int l = 0; l < 12; ++l) vals[l][ci] = 0;
        }
    }
    #pragma unroll
    for (int l = 0; l < 12; ++l) {
        u16* dst = xq + ((size_t)(b * 12 + l) * 512 + v) * 48 + cg * 12;
        u16x4 a = { vals[l][0], vals[l][1], vals[l][2], vals[l][3] };
        u16x4 c4 = { vals[l][4], vals[l][5], vals[l][6], vals[l][7] };
        u16x4 d = { vals[l][8], vals[l][9], vals[l][10], vals[l][11] };
        *(u16x4*)(dst) = a;
        *(u16x4*)(dst + 4) = c4;
        *(u16x4*)(dst + 8) = d;
    }
}

// ---------------- K1: fused 7-way projection of x ----------------
__global__ __launch_bounds__(256) void proj_x(
    const u16* __restrict__ xq, const float* __restrict__ W,
    u16* __restrict__ P1, u16* __restrict__ P2, u16* __restrict__ proj0)
{
    __shared__ u16 sA[144 * 104];
    __shared__ u16 sB[2][2 * 64 * 48];

    const int t = threadIdx.x, lane = t & 63, wid = t >> 6;
    const int b = blockIdx.y, v0 = blockIdx.x * 64;

    for (int id = t; id < 144 * 5; id += 256) {
        int m = id / 5, c0 = (id % 5) * 8;
        u16x8 e = {}, o8 = {};
        if (m < 140) {
            int o = m % 20, sg = m / 20;
            const float* wp = W + o * 560 + sg * 80 + c0 * 2;
            float4 a = *(const float4*)wp;
            float4 bb = *(const float4*)(wp + 4);
            float4 c = *(const float4*)(wp + 8);
            float4 d = *(const float4*)(wp + 12);
            e[0] = f2bf(a.x);  o8[0] = f2bf(a.y);  e[1] = f2bf(a.z);  o8[1] = f2bf(a.w);
            e[2] = f2bf(bb.x); o8[2] = f2bf(bb.y); e[3] = f2bf(bb.z); o8[3] = f2bf(bb.w);
            e[4] = f2bf(c.x);  o8[4] = f2bf(c.y);  e[5] = f2bf(c.z);  o8[5] = f2bf(c.w);
            e[6] = f2bf(d.x);  o8[6] = f2bf(d.y);  e[7] = f2bf(d.z);  o8[7] = f2bf(d.w);
        }
        *(u16x8*)(&sA[m * 104 + c0]) = e;
        *(u16x8*)(&sA[m * 104 + 40 + c0]) = o8;
    }
    for (int id = t; id < 144 * 3; id += 256) {
        int m = id / 3, k0 = 80 + (id % 3) * 8;
        u16x8 z = {};
        *(u16x8*)(&sA[m * 104 + k0]) = z;
    }

    auto stage = [&](int l, int buf) {
        u16* dst = &sB[buf][0];
        #pragma unroll
        for (int i = 0; i < 3; ++i) {
            int op = wid * 3 + i;
            int tap = op / 6, rem = op % 6;
            const u16* src = xq + ((size_t)(b * 12 + l + 2 * tap) * 512 + v0) * 48
                             + rem * 512 + lane * 8;
            GLD_LDS16(src, dst + tap * 3072 + rem * 512);
        }
    };

    stage(0, 0);
    __syncthreads();

    const int lr = lane & 15, q = lane >> 4;
    bf16x8 af[9][3];
    #pragma unroll
    for (int mf = 0; mf < 9; ++mf)
        #pragma unroll
        for (int s = 0; s < 3; ++s)
            af[mf][s] = *(const bf16x8*)(&sA[(mf * 16 + lr) * 104 + s * 32 + q * 8]);

    const int voff = (wid * 16 + lr) * 48;
    int boff[3];
    #pragma unroll
    for (int s = 0; s < 3; ++s) {
        int k = s * 32 + q * 8;
        int tap, c;
        if (k < 40)      { tap = 0; c = k; }
        else if (k < 80) { tap = 1; c = k - 40; }
        else             { tap = 1; c = 40; }
        boff[s] = tap * 3072 + voff + c;
    }

    const int v = v0 + wid * 16 + lr;
    for (int l = 0; l < 10; ++l) {
        const int cur = l & 1;
        if (l < 9) stage(l + 1, cur ^ 1);

        const u16* bb = &sB[cur][0];
        bf16x8 xf[3];
        #pragma unroll
        for (int s = 0; s < 3; ++s) xf[s] = *(const bf16x8*)(bb + boff[s]);

        f32x4 acc[9] = {};
        #pragma unroll
        for (int s = 0; s < 3; ++s)
            #pragma unroll
            for (int mf = 0; mf < 9; ++mf)
                acc[mf] = __builtin_amdgcn_mfma_f32_16x16x32_bf16(
                    af[mf][s], xf[s], acc[mf], 0, 0, 0);

        #pragma unroll
        for (int mf = 0; mf < 9; ++mf)
            #pragma unroll
            for (int i = 0; i < 4; ++i) {
                int m = mf * 16 + q * 4 + i;
                if (m < 140) {
                    int o = m % 20, sg = m / 20;
                    float val = acc[mf][i];
                    if (sg == 0) {
                        proj0[((size_t)(b * 20 + o) * 10 + l) * 512 + v] = f2bf(val);
                    } else {
                        int s2 = (sg - 1) >> 1;
                        u16* dst = ((sg - 1) & 1) ? P2 : P1;
                        dst[((size_t)(s2 * 32 + b) * 200 + o * 10 + l) * 512 + v] = f2bf(val);
                    }
                }
            }
        __syncthreads();
    }
}

// ---------------- shared GEMM body: 2-phase DMA, full-col tile 128v x 224c ----------------
// BK=32, 16 K-steps, 4 waves (wave = 32v x 224c = 2 af x 14 xf = 28 MFMA/step).
// A staged ONCE per slab (no col-split). LDS 60KB -> 2 blocks/CU, grid 384 all-resident.
// EPI=0: T := acc + P1 (in-place RMW); EPI=1: plain bf16 store.
template <int EPI>
__device__ __forceinline__ void gemm_body(
    const float* __restrict__ A0, const float* __restrict__ A1, const float* __restrict__ A2,
    const u16* __restrict__ Xsrc, u16* __restrict__ Odst)
{
    __shared__ char smem[61440];             // 60 KB
    float* sAf = (float*)smem;               // [2][128*32] f32 = 32 KB
    u16*   sXs = (u16*)(smem + 32768);       // [2][224*32] u16 = 28 KB

    // XCD swizzle: 384 blocks -> each XCD 48 eids = 12 whole z's
    const int bid = blockIdx.x;
    const int eid = (bid & 7) * 48 + (bid >> 3);
    const int z = eid >> 2;
    const int vblk = (eid & 3) * 128;
    const int s = z >> 5, b = z & 31;

    const float* Af = (s == 0 ? A0 : (s == 1 ? A1 : A2)) + (size_t)b * 512 * 512;
    const u16* Xb = Xsrc + (size_t)z * 200 * 512;

    const int t = threadIdx.x;
    const int lane = t & 63, wid = t >> 6;
    const int lr = lane & 15, q = lane >> 4;
    const int kc0 = q * 2;                   // A chunk pair base (16B chunks)

    auto stage = [&](int kt, int buf) {
        const int w0 = kt * 32;
        float* ab = sAf + buf * 4096;
        u16*   xb = sXs + buf * 7168;
        // A: 128 rows x 128B = 16 ops; wave does 4. Chunk-XOR swizzled source.
        #pragma unroll
        for (int i = 0; i < 4; ++i) {
            int op  = wid * 4 + i;
            int row = op * 8 + (lane >> 3);
            int pc  = lane & 7;
            const float* src = Af + (size_t)(vblk + row) * 512 + w0 + ((pc ^ (row & 7)) << 2);
            GLD_LDS16(src, ab + op * 256);
        }
        // X: 224 rows x 64B = 14 ops; waves do 3-4 (rows >=200 overflow-read, unused cols).
        #pragma unroll
        for (int i = 0; i < 4; ++i) {
            int op = wid + i * 4;
            if (op < 14) {
                int row = op * 16 + (lane >> 2);
                int ch  = lane & 3;
                const u16* src = Xb + (size_t)row * 512 + w0 + ch * 8;
                GLD_LDS16(src, xb + op * 512);
            }
        }
    };

    f32x4 acc[14][2] = {};

    stage(0, 0);
    __syncthreads();

    for (int kt = 0; kt < 16; ++kt) {
        const int cur = kt & 1;
        if (kt < 15) stage(kt + 1, cur ^ 1);

        bf16x8 af[2];
        #pragma unroll
        for (int mf = 0; mf < 2; ++mf) {
            int r = wid * 32 + mf * 16 + lr;
            const float* rb = sAf + cur * 4096 + r * 32;
            f32x4 a0 = *(const f32x4*)(rb + ((kc0 ^ (r & 7)) << 2));
            f32x4 a1 = *(const f32x4*)(rb + (((kc0 + 1) ^ (r & 7)) << 2));
            union { u16x8 u; bf16x8 bv; } cv;
            cv.u = (u16x8){ f2bf(a0[0]), f2bf(a0[1]), f2bf(a0[2]), f2bf(a0[3]),
                            f2bf(a1[0]), f2bf(a1[1]), f2bf(a1[2]), f2bf(a1[3]) };
            af[mf] = cv.bv;
        }
        #pragma unroll
        for (int cf = 0; cf < 14; ++cf) {
            bf16x8 xf = *(const bf16x8*)(sXs + cur * 7168 + (cf * 16 + lr) * 32 + q * 8);
            #pragma unroll
            for (int mf = 0; mf < 2; ++mf)
                acc[cf][mf] = __builtin_amdgcn_mfma_f32_16x16x32_bf16(
                    xf, af[mf], acc[cf][mf], 0, 0, 0);
        }
        __syncthreads();
    }

    // LDS-transpose epilogue: acc -> eb[col][v] (stride 132), coalesced u16x8 out.
    u16* eb = (u16*)smem;                    // 224*132*2 = 59136 B <= 60 KB
    #pragma unroll
    for (int cf = 0; cf < 14; ++cf)
        #pragma unroll
        for (int mf = 0; mf < 2; ++mf)
            #pragma unroll
            for (int i = 0; i < 4; ++i) {
                int col = cf * 16 + q * 4 + i;            // 0..223
                int vl  = wid * 32 + mf * 16 + lr;        // 0..127
                eb[col * 132 + vl] = f2bf(acc[cf][mf][i]);
            }
    __syncthreads();
    u16* Oz = Odst + (size_t)z * 200 * 512;
    for (int id = t; id < 224 * 16; id += 256) {
        int col = id >> 4, ch = id & 15;
        if (col < 200) {
            u16x8 tv = *(const u16x8*)(&eb[col * 132 + ch * 8]);
            size_t gidx = (size_t)col * 512 + vblk + ch * 8;
            if (EPI == 0) {
                u16x8 pv = *(const u16x8*)(Oz + gidx);
                u16x8 out;
                #pragma unroll
                for (int j = 0; j < 8; ++j) out[j] = f2bf(bf2f(tv[j]) + bf2f(pv[j]));
                *(u16x8*)(Oz + gidx) = out;
            } else {
                *(u16x8*)(Oz + gidx) = tv;
            }
        }
    }
}

__global__ __launch_bounds__(256) void gemm_t(
    const float* __restrict__ A0, const float* __restrict__ A1, const float* __restrict__ A2,
    const u16* __restrict__ P2, u16* __restrict__ T)
{
    gemm_body<0>(A0, A1, A2, P2, T);
}

__global__ __launch_bounds__(256) void gemm_yp(
    const float* __restrict__ A0, const float* __restrict__ A1, const float* __restrict__ A2,
    const u16* __restrict__ T, u16* __restrict__ Ypart)
{
    gemm_body<1>(A0, A1, A2, T, Ypart);
}

// ---------------- K4: y = bias + proj0 + sum_s Ypart[s] ----------------
__global__ __launch_bounds__(256) void reduce_y(
    const u16* __restrict__ Ypart, const u16* __restrict__ proj0,
    const float* __restrict__ bias, float* __restrict__ y)
{
    int i = blockIdx.x * 256 + threadIdx.x;   // over 32*20*512
    if (i >= 32 * 20 * 512) return;
    int v = i & 511;
    int r = i >> 9;                           // b*20 + o
    int o = r % 20, b = r / 20;
    float bb = bias[o];
    float* yp = y + ((size_t)r * 512 + v) * 10;
    #pragma unroll
    for (int l = 0; l < 10; ++l) {
        float sum = bb + bf2f(proj0[((size_t)r * 10 + l) * 512 + v]);
        #pragma unroll
        for (int s = 0; s < 3; ++s)
            sum += bf2f(Ypart[((size_t)(s * 32 + b) * 200 + o * 10 + l) * 512 + v]);
        yp[l] = sum;
    }
}

extern "C" void kernel_launch(void* const* d_in, const int* in_sizes, int n_in,
                              void* d_out, int out_size, void* d_ws, size_t ws_size,
                              hipStream_t stream) {
    const float* x    = (const float*)d_in[0];
    const float* A0   = (const float*)d_in[1];
    const float* A1   = (const float*)d_in[2];
    const float* A2   = (const float*)d_in[3];
    const float* W    = (const float*)d_in[4];
    const float* bias = (const float*)d_in[5];
    float* y = (float*)d_out;

    // ws (all bf16): P1/T 19.66MB | P2 19.66MB | proj0 6.55MB | Ypart 19.66MB
    // xq (18.87MB) aliases Ypart (dead before gemm_yp). Total 65.5MB.
    const size_t PSZ = (size_t)96 * 200 * 512;
    u16* P1 = (u16*)d_ws;
    u16* P2 = P1 + PSZ;
    u16* proj0 = P2 + PSZ;
    u16* Ypart = proj0 + (size_t)32 * 20 * 10 * 512;
    u16* xq = Ypart;                          // alias

    xpose<<<dim3(8, 32), 256, 0, stream>>>(x, xq);
    proj_x<<<dim3(8, 32), 256, 0, stream>>>(xq, W, P1, P2, proj0);
    gemm_t<<<dim3(384), 256, 0, stream>>>(A0, A1, A2, P2, P1);       // T := P1 + A@P2
    gemm_yp<<<dim3(384), 256, 0, stream>>>(A0, A1, A2, P1, Ypart);   // Ypart = A@T
    reduce_y<<<dim3(1280), 256, 0, stream>>>(Ypart, proj0, bias, y);
}